// Round 13
// baseline (6278.261 us; speedup 1.0000x reference)
//
#include <hip/hip_runtime.h>
#include <math.h>

using f16x8 = __attribute__((ext_vector_type(8))) _Float16;
using f32x4 = __attribute__((ext_vector_type(4))) float;
using u32x4 = __attribute__((ext_vector_type(4))) unsigned int;
using u16   = unsigned short;

// ---------------- problem constants ----------------
constexpr int Tst = 60;

// ---------------- workspace: A-fragment streams (layout identical to rounds 4-12) ----
constexpr int FR      = 512;
constexpr int N_AG0   = 64 * 9  * 2 * FR;
constexpr int N_AL0   = 64 * 9  * 2 * FR;
constexpr int N_AL1   = 64 * 17 * 2 * FR;
constexpr int N_AH1   = 4  * 9  * 2 * FR;
constexpr int OFF_AG0 = 0;
constexpr int OFF_AL0 = OFF_AG0 + N_AG0;
constexpr int OFF_AL1 = OFF_AL0 + N_AL0;
constexpr int OFF_AH1 = OFF_AL1 + N_AL1;
constexpr int WS_U16  = OFF_AH1 + N_AH1;          // 2,330,624 u16

// ---------------- h2-only exchange slabs + padded flags ----------------
// H[bc 64][par 2] slab of [kt 8][sb 2][nt 2][512] u16 = 32 KB (full h2, 256 units x 32 rows)
constexpr int N_HSLAB = 8 * 2 * 2 * 512;          // 16384 u16 = 32 KB
constexpr int OFF_H   = WS_U16;
constexpr int N_H     = 64 * 2 * N_HSLAB;         // 2,097,152 u16 = 4 MB
constexpr int OFF_FLG = OFF_H + N_H;
constexpr int FLG_STRIDE = 32;                    // ints (128 B line per flag)
constexpr int N_FLAGS_I  = 64 * 4 * FLG_STRIDE;   // 8192 ints
constexpr size_t WS_BYTES = (size_t)OFF_FLG * 2 + (size_t)N_FLAGS_I * sizeof(int);

__device__ __forceinline__ u16 hbits(_Float16 h) {
    union { _Float16 h; u16 u; } x; x.h = h; return x.u;
}

// ---------------- weight repack (verbatim — validated rounds 4-12) ----------------
__global__ void prep_kernel(const float* __restrict__ Wih0, const float* __restrict__ Whh0,
                            const float* __restrict__ bih0, const float* __restrict__ bhh0,
                            const float* __restrict__ Wih1, const float* __restrict__ Whh1,
                            const float* __restrict__ bih1, const float* __restrict__ bhh1,
                            const float* __restrict__ Wout1, const float* __restrict__ bout1,
                            u16* __restrict__ ws) {
    int i = blockIdx.x * 256 + threadIdx.x;
    if (i >= WS_U16) return;
    int arr, idx = i, KT;
    if (i < OFF_AL0)      { arr = 0; KT = 9; }
    else if (i < OFF_AL1) { arr = 1; idx -= OFF_AL0; KT = 9; }
    else if (i < OFF_AH1) { arr = 2; idx -= OFF_AL1; KT = 17; }
    else                  { arr = 3; idx -= OFF_AH1; KT = 9; }
    const int per_mt = KT * 2 * FR;
    const int mt = idx / per_mt;
    int r = idx - mt * per_mt;
    const int kt = r / (2 * FR);
    r -= kt * 2 * FR;
    const int s    = r >> 9;
    const int f    = r & 511;
    const int lane = f >> 3, j = f & 7;
    const int m    = mt * 16 + (lane & 15);
    const int k_in = ((lane >> 4) << 3) + j;

    float v = 0.f;
    if (arr == 3) {
        if (kt < 8) v = Wout1[m * 256 + kt * 32 + k_in];
        else if (k_in == 0) v = bout1[m];
    } else {
        const int unit = m >> 2, gate = m & 3, row = gate * 256 + unit;
        if (arr == 0) {
            if (kt < 8) v = Wih0[row * 258 + 2 + kt * 32 + k_in];
            else if (k_in == 0) v = bih0[row] + bhh0[row];
        } else if (arr == 1) {
            if (kt < 8) v = Whh0[row * 256 + kt * 32 + k_in];
            else if (k_in < 2) v = Wih0[row * 258 + k_in];
        } else {
            if (kt < 8)         v = Wih1[row * 256 + kt * 32 + k_in];
            else if (kt < 16)   v = Whh1[row * 256 + (kt - 8) * 32 + k_in];
            else if (k_in == 0) v = bih1[row] + bhh1[row];
        }
    }
    _Float16 hi = (_Float16)v;
    ws[i] = (s == 0) ? hbits(hi) : hbits((_Float16)(v - (float)hi));
}

// ---------------- helpers ----------------
__device__ __forceinline__ f32x4 MF(f16x8 a, f16x8 b, f32x4 c) {
    return __builtin_amdgcn_mfma_f32_16x16x32_f16(a, b, c, 0, 0, 0);
}
__device__ __forceinline__ float sigm(float x) { return 1.f / (1.f + __expf(-x)); }
__device__ __forceinline__ float tanh_(float x) {
    float e = __expf(-2.f * fabsf(x));
    float r = (1.f - e) / (1.f + e);
    return copysignf(r, x);
}
__device__ __forceinline__ float lstm_out(f32x4 g, float& c) {
    float iv = sigm(g[0]), fv = sigm(g[1]), gv = tanh_(g[2]), ov = sigm(g[3]);
    c = fmaf(fv, c, iv * gv);
    return ov * tanh_(c);
}
__device__ __forceinline__ void waitcnt0() {
    asm volatile("s_waitcnt vmcnt(0)" ::: "memory");
}
__device__ __forceinline__ void ld4_sc(const u32x4* p, u32x4& v) {
    asm volatile("global_load_dwordx4 %0, %1, off sc0 sc1" : "=v"(v) : "v"(p));
}
__device__ __forceinline__ void st4_sc(u32x4* p, u32x4 v) {
    asm volatile("global_store_dwordx4 %0, %1, off sc0 sc1" :: "v"(p), "v"(v) : "memory");
}
// 32 KB coherent global->LDS stage; 512 threads x 4 x 16 B
__device__ __forceinline__ void stage32k(const u16* g, u16* lds, int t) {
    const u32x4* s = (const u32x4*)g;
    u32x4 v0, v1, v2, v3;
    ld4_sc(s + t, v0); ld4_sc(s + t + 512, v1);
    ld4_sc(s + t + 1024, v2); ld4_sc(s + t + 1536, v3);
    waitcnt0();
    __builtin_amdgcn_sched_barrier(0);
    u32x4* d = (u32x4*)lds;
    d[t] = v0; d[t + 512] = v1; d[t + 1024] = v2; d[t + 1536] = v3;
}
__device__ __forceinline__ void spin_ge(int* p, int target) {
    while (__hip_atomic_load(p, __ATOMIC_RELAXED, __HIP_MEMORY_SCOPE_AGENT) < target)
        __builtin_amdgcn_s_sleep(1);
}
__device__ __forceinline__ size_t hidx(int bc, int par) {
    return (size_t)(bc * 2 + par) * N_HSLAB;
}
__device__ __forceinline__ int* fptr(int* flags, int bc, int uc) {
    return flags + (size_t)(bc * 4 + uc) * FLG_STRIDE;
}

// ---------------- main kernel: 256 blocks = 64 bc x 4 uc, 512 thr = 8 waves ----
// L0-REPLICATED: every block computes FULL h1 (256 units) for its 32 rows locally
// (X lives only in LDS — h1 never crosses blocks). Only h2 is exchanged: one
// spin + one 32 KB stage + one 8 KB store per step. The staged Y serves both
// the deferred head(s-1) and phase B's Whh1 term.
// uc = bid&3 -> one unit-chunk per XCD; XCD hot set = AL0-full + AL1/AH slices
// ~3 MB < 4 MB L2 (residency pattern validated R5/R9).
__global__ __launch_bounds__(512, 2) void lstm_main(
    const float* __restrict__ env, const float* __restrict__ hist,
    const float* __restrict__ goal, const float* __restrict__ cpos,
    const float* __restrict__ Wproj, const float* __restrict__ b_proj,
    const float* __restrict__ Wout2, const float* __restrict__ b_out2,
    u16* __restrict__ wsu, float* __restrict__ out) {

    __shared__ __align__(16) unsigned char smem[89600];
    u16*   X    = (u16*)smem;                     // 32 KB: h1 full (LOCAL, retained)
    u16*   Y    = (u16*)(smem + 32768);           // 32 KB: h2(s-1) full (staged)
    u16*   hSt  = (u16*)(smem + 65536);           // 8 KB: own h2-slice coalesce
    float* mlpL = (float*)(smem + 73728);         // [32][68] f32 = 8704 B
    float* part = (float*)(smem + 82432);         // [256] f32
    u16*   posF = (u16*)(smem + 83456);           // [sb2][nt2][512] = 4 KB
    u16*   onesF= (u16*)(smem + 87552);           // [sb2][512] = 2 KB
    float* xbuf = (float*)smem;                   // prologue overlay [386][32] (49408 B)
    float* ctxL = (float*)(smem + 49408);         // prologue overlay [256][32] (ends 82176)

    const int t  = threadIdx.x;
    const int w  = t >> 6;                        // 0..7
    const int l  = t & 63;
    const int bc = (int)blockIdx.x >> 2;          // 0..63
    const int uc = (int)blockIdx.x & 3;           // XCD&3 -> AL1/AH slice partition
    const int row0 = bc * 32;

    u16* Hb = wsu + OFF_H;
    int* flags = (int*)(wsu + OFF_FLG);

    // L0 full: wave w owns mt w*8 .. w*8+7 (units w*32 .. w*32+31)
    const u16* AG0w = wsu + OFF_AG0 + (size_t)(w * 8) * (9 * 1024) + l * 8;
    const u16* A0w  = wsu + OFF_AL0 + (size_t)(w * 8) * (9 * 1024) + l * 8;
    // L1 slice: wave w owns mt uc*16 + 2w, 2w+1 (8 units)
    const u16* A1w  = wsu + OFF_AL1 + (size_t)(uc * 16 + 2 * w) * (17 * 1024) + l * 8;
    const u16* AHw  = wsu + OFF_AH1 + (size_t)(w & 3) * (9 * 1024) + l * 8;
    const int  nth  = w >> 2;                     // head nt for this wave

    // ---- P1: stage ctx_in [k][r] (32 rows) ----
    for (int idx = t; idx < 386 * 32; idx += 512) {
        int r = idx & 31, k = idx >> 5;
        int gr = row0 + r; float v;
        if (k < 256)      v = env[gr * 256 + k];
        else if (k < 384) v = hist[gr * 128 + (k - 256)];
        else              v = goal[gr * 2 + (k - 384)];
        xbuf[k * 32 + r] = v;
    }
    __syncthreads();

    // ---- P2: context fp32 (256 units x 32 rows; thread = (u, 16-row half)) ----
    {
        const int u = t & 255, rh = t >> 8;       // rh 0..1
        float acc[16];
        float bp = b_proj[u];
#pragma unroll
        for (int rr = 0; rr < 16; ++rr) acc[rr] = bp;
        for (int k = 0; k < 386; ++k) {
            float wv = Wproj[u * 386 + k];
            const float* xr = &xbuf[k * 32 + rh * 16];
#pragma unroll
            for (int rr = 0; rr < 16; ++rr) acc[rr] = fmaf(xr[rr], wv, acc[rr]);
        }
#pragma unroll
        for (int rr = 0; rr < 16; ++rr) ctxL[u * 32 + rh * 16 + rr] = acc[rr];
    }
    __syncthreads();

    // ---- P3a: X <- ctx (B-fragment hi/lo form), LOCAL only ----
    for (int idx = t; idx < 16384; idx += 512) {
        int f = idx & 511, nt = (idx >> 9) & 1, sb = (idx >> 10) & 1, kt = idx >> 11;
        int lane = f >> 3, j = f & 7;
        int k_in = ((lane >> 4) << 3) + j;
        int unit = kt * 32 + k_in;
        float v = ctxL[unit * 32 + nt * 16 + (lane & 15)];
        _Float16 hi = (_Float16)v;
        X[idx] = sb ? hbits((_Float16)(v - (float)hi)) : hbits(hi);
    }
    __syncthreads();                              // ctxL dead

    // ---- P3b: Y <- X (h2(-1) = ctx); P4: posF + onesF ----
    for (int i = t; i < 2048; i += 512) ((u32x4*)Y)[i] = ((const u32x4*)X)[i];
    for (int idx = t; idx < 2048; idx += 512) {
        int f = idx & 511, nt = (idx >> 9) & 1, sb = idx >> 10;
        int lane = f >> 3, j = f & 7;
        int k_in = ((lane >> 4) << 3) + j;
        u16 val = 0;
        if (k_in < 2) {
            float pv = cpos[(row0 + nt * 16 + (lane & 15)) * 2 + k_in];
            _Float16 hi = (_Float16)pv;
            val = sb ? hbits((_Float16)(pv - (float)hi)) : hbits(hi);
        }
        posF[(sb * 2 + nt) * 512 + f] = val;
    }
    for (int idx = t; idx < 1024; idx += 512) {
        int f = idx & 511, sb = idx >> 9;
        int lane = f >> 3, j = f & 7;
        int k_in = ((lane >> 4) << 3) + j;
        onesF[sb * 512 + f] = (sb == 0 && k_in == 0) ? hbits((_Float16)1.0f) : (u16)0;
    }
    __syncthreads();

    // ---- P5: G0c (ctx contribution + L0 biases), full 256 units ----
    f32x4 G0[8][2];
#pragma unroll
    for (int mm = 0; mm < 8; ++mm) { G0[mm][0] = f32x4{0,0,0,0}; G0[mm][1] = f32x4{0,0,0,0}; }
#pragma unroll
    for (int kt = 0; kt < 8; ++kt) {
        f16x8 bh0 = *(const f16x8*)&X[((kt*2+0)*2+0)*512 + l*8];
        f16x8 bl0 = *(const f16x8*)&X[((kt*2+1)*2+0)*512 + l*8];
        f16x8 bh1 = *(const f16x8*)&X[((kt*2+0)*2+1)*512 + l*8];
        f16x8 bl1 = *(const f16x8*)&X[((kt*2+1)*2+1)*512 + l*8];
#pragma unroll
        for (int mm = 0; mm < 8; ++mm) {
            const u16* p = AG0w + (size_t)(mm * 9 + kt) * 1024;
            f16x8 ah = *(const f16x8*)p, al = *(const f16x8*)(p + 512);
            G0[mm][0] = MF(ah,bh0,G0[mm][0]); G0[mm][0] = MF(ah,bl0,G0[mm][0]); G0[mm][0] = MF(al,bh0,G0[mm][0]);
            G0[mm][1] = MF(ah,bh1,G0[mm][1]); G0[mm][1] = MF(ah,bl1,G0[mm][1]); G0[mm][1] = MF(al,bh1,G0[mm][1]);
        }
    }
    {
        f16x8 bh = *(const f16x8*)&onesF[l*8];
        f16x8 bl = *(const f16x8*)&onesF[512 + l*8];
#pragma unroll
        for (int mm = 0; mm < 8; ++mm) {
            const u16* p = AG0w + (size_t)(mm * 9 + 8) * 1024;
            f16x8 ah = *(const f16x8*)p, al = *(const f16x8*)(p + 512);
            G0[mm][0] = MF(ah,bh,G0[mm][0]); G0[mm][0] = MF(ah,bl,G0[mm][0]); G0[mm][0] = MF(al,bh,G0[mm][0]);
            G0[mm][1] = MF(ah,bh,G0[mm][1]); G0[mm][1] = MF(ah,bl,G0[mm][1]); G0[mm][1] = MF(al,bh,G0[mm][1]);
        }
    }
    float c1[8][2], c2[2][2];
#pragma unroll
    for (int mm = 0; mm < 8; ++mm) { c1[mm][0] = 0.f; c1[mm][1] = 0.f; }
    c2[0][0] = c2[0][1] = c2[1][0] = c2[1][1] = 0.f;

    // ================= time loop =================
    for (int s = 0; s < Tst; ++s) {
        const int par = s & 1;

        // ===== A1: L0 kt0-7 (reads X = h1(s-1)) — dependency-free, hides spin =====
        f32x4 a[8][2];
#pragma unroll
        for (int mm = 0; mm < 8; ++mm) { a[mm][0] = G0[mm][0]; a[mm][1] = G0[mm][1]; }
#pragma unroll
        for (int kt = 0; kt < 8; ++kt) {
            f16x8 bh0 = *(const f16x8*)&X[((kt*2+0)*2+0)*512 + l*8];
            f16x8 bl0 = *(const f16x8*)&X[((kt*2+1)*2+0)*512 + l*8];
            f16x8 bh1 = *(const f16x8*)&X[((kt*2+0)*2+1)*512 + l*8];
            f16x8 bl1 = *(const f16x8*)&X[((kt*2+1)*2+1)*512 + l*8];
#pragma unroll
            for (int mm = 0; mm < 8; ++mm) {
                const u16* p = A0w + (size_t)(mm * 9 + kt) * 1024;
                f16x8 ah = *(const f16x8*)p, al = *(const f16x8*)(p + 512);
                a[mm][0] = MF(ah,bh0,a[mm][0]); a[mm][0] = MF(ah,bl0,a[mm][0]); a[mm][0] = MF(al,bh0,a[mm][0]);
                a[mm][1] = MF(ah,bh1,a[mm][1]); a[mm][1] = MF(ah,bl1,a[mm][1]); a[mm][1] = MF(al,bh1,a[mm][1]);
            }
        }

        // ===== sync + stage Y = h2(s-1) + head(s-1) =====
        if (s >= 1) {
            if (t < 4) spin_ge(fptr(flags, bc, t), s);
            __syncthreads();                      // A1 X-reads done; flag seen
            stage32k(Hb + hidx(bc, par ^ 1), Y, t);
            __syncthreads();                      // Y ready
            {   // head: mlp = relu(h2(s-1) @ Wout1^T + b_out1)
                f32x4 pv = {0,0,0,0};
#pragma unroll
                for (int kt = 0; kt < 8; ++kt) {
                    f16x8 bh = *(const f16x8*)&Y[((kt*2+0)*2+nth)*512 + l*8];
                    f16x8 bl = *(const f16x8*)&Y[((kt*2+1)*2+nth)*512 + l*8];
                    const u16* p = AHw + kt * 1024;
                    f16x8 ah = *(const f16x8*)p, al = *(const f16x8*)(p + 512);
                    pv = MF(ah, bh, pv); pv = MF(ah, bl, pv); pv = MF(al, bh, pv);
                }
                {
                    f16x8 bh = *(const f16x8*)&onesF[l*8];
                    f16x8 bl = *(const f16x8*)&onesF[512 + l*8];
                    const u16* p = AHw + 8 * 1024;
                    f16x8 ah = *(const f16x8*)p, al = *(const f16x8*)(p + 512);
                    pv = MF(ah, bh, pv); pv = MF(ah, bl, pv); pv = MF(al, bh, pv);
                }
#pragma unroll
                for (int r = 0; r < 4; ++r) pv[r] = fmaxf(pv[r], 0.f);
                *(f32x4*)&mlpL[(nth * 16 + (l & 15)) * 68 + (w & 3) * 16 + (l >> 4) * 4] = pv;
            }
            __syncthreads();                      // mlpL ready
            if (t < 256) {                        // head2 partials (q4, r32, o2)
                const int q = t >> 6, idx = t & 63, r = idx >> 1, o = idx & 1;
                float acc = 0.f;
#pragma unroll
                for (int k = 0; k < 16; ++k)
                    acc = fmaf(mlpL[r * 68 + q * 16 + k], Wout2[o * 64 + q * 16 + k], acc);
                part[t] = acc;
            }
            __syncthreads();
            if (t < 64) {
                const int r = t >> 1, o = t & 1;
                float acc = b_out2[o] + part[t] + part[64 + t] + part[128 + t] + part[192 + t];
                if (uc == 0) out[((size_t)(row0 + r) * Tst + (s - 1)) * 2 + o] = acc;
                _Float16 hi = (_Float16)acc;
                posF[(0 * 2 + (r >> 4)) * 512 + (r & 15) * 8 + o] = hbits(hi);
                posF[(2 + (r >> 4)) * 512 + (r & 15) * 8 + o] = hbits((_Float16)(acc - (float)hi));
            }
            __syncthreads();                      // posF(s) ready
        } else {
            __syncthreads();                      // A1 X-reads done before X overwrite
        }

        // ===== A3: pos column + lstm_out -> write X = h1(s) (LOCAL) =====
        {
            f16x8 bh0 = *(const f16x8*)&posF[(0*2+0)*512 + l*8];
            f16x8 bh1 = *(const f16x8*)&posF[(0*2+1)*512 + l*8];
            f16x8 bl0 = *(const f16x8*)&posF[(1*2+0)*512 + l*8];
            f16x8 bl1 = *(const f16x8*)&posF[(1*2+1)*512 + l*8];
#pragma unroll
            for (int mm = 0; mm < 8; ++mm) {
                const u16* p = A0w + (size_t)(mm * 9 + 8) * 1024;
                f16x8 ah = *(const f16x8*)p, al = *(const f16x8*)(p + 512);
                a[mm][0] = MF(ah,bh0,a[mm][0]); a[mm][0] = MF(ah,bl0,a[mm][0]); a[mm][0] = MF(al,bh0,a[mm][0]);
                a[mm][1] = MF(ah,bh1,a[mm][1]); a[mm][1] = MF(ah,bl1,a[mm][1]); a[mm][1] = MF(al,bh1,a[mm][1]);
            }
#pragma unroll
            for (int mm = 0; mm < 8; ++mm)
#pragma unroll
                for (int nt = 0; nt < 2; ++nt) {
                    float h1n = lstm_out(a[mm][nt], c1[mm][nt]);
                    const int unit = (w * 8 + mm) * 4 + (l >> 4);   // 0..255
                    const int ktx = unit >> 5, ki = unit & 31;
                    const int f = ((l & 15) + 16 * (ki >> 3)) * 8 + (ki & 7);
                    _Float16 hi = (_Float16)h1n;
                    X[((ktx*2+0)*2+nt)*512 + f] = hbits(hi);
                    X[((ktx*2+1)*2+nt)*512 + f] = hbits((_Float16)(h1n - (float)hi));
                }
        }
        __syncthreads();                          // X = h1(s) complete

        // ===== B: h2(s) slice = Wih1@h1(s) + Whh1@Y + bias =====
        {
            f32x4 b2[2][2] = {{{0,0,0,0},{0,0,0,0}},{{0,0,0,0},{0,0,0,0}}};
#pragma unroll
            for (int kt = 0; kt < 8; ++kt) {
                f16x8 bh0 = *(const f16x8*)&X[((kt*2+0)*2+0)*512 + l*8];
                f16x8 bl0 = *(const f16x8*)&X[((kt*2+1)*2+0)*512 + l*8];
                f16x8 bh1 = *(const f16x8*)&X[((kt*2+0)*2+1)*512 + l*8];
                f16x8 bl1 = *(const f16x8*)&X[((kt*2+1)*2+1)*512 + l*8];
#pragma unroll
                for (int mm = 0; mm < 2; ++mm) {
                    const u16* p = A1w + (size_t)(mm * 17 + kt) * 1024;
                    f16x8 ah = *(const f16x8*)p, al = *(const f16x8*)(p + 512);
                    b2[mm][0] = MF(ah,bh0,b2[mm][0]); b2[mm][0] = MF(ah,bl0,b2[mm][0]); b2[mm][0] = MF(al,bh0,b2[mm][0]);
                    b2[mm][1] = MF(ah,bh1,b2[mm][1]); b2[mm][1] = MF(ah,bl1,b2[mm][1]); b2[mm][1] = MF(al,bh1,b2[mm][1]);
                }
            }
#pragma unroll
            for (int ks = 0; ks < 8; ++ks) {
                f16x8 bh0 = *(const f16x8*)&Y[((ks*2+0)*2+0)*512 + l*8];
                f16x8 bl0 = *(const f16x8*)&Y[((ks*2+1)*2+0)*512 + l*8];
                f16x8 bh1 = *(const f16x8*)&Y[((ks*2+0)*2+1)*512 + l*8];
                f16x8 bl1 = *(const f16x8*)&Y[((ks*2+1)*2+1)*512 + l*8];
#pragma unroll
                for (int mm = 0; mm < 2; ++mm) {
                    const u16* p = A1w + (size_t)(mm * 17 + 8 + ks) * 1024;
                    f16x8 ah = *(const f16x8*)p, al = *(const f16x8*)(p + 512);
                    b2[mm][0] = MF(ah,bh0,b2[mm][0]); b2[mm][0] = MF(ah,bl0,b2[mm][0]); b2[mm][0] = MF(al,bh0,b2[mm][0]);
                    b2[mm][1] = MF(ah,bh1,b2[mm][1]); b2[mm][1] = MF(ah,bl1,b2[mm][1]); b2[mm][1] = MF(al,bh1,b2[mm][1]);
                }
            }
            {   // bias column (kt 16)
                f16x8 bh = *(const f16x8*)&onesF[l*8];
                f16x8 bl = *(const f16x8*)&onesF[512 + l*8];
#pragma unroll
                for (int mm = 0; mm < 2; ++mm) {
                    const u16* p = A1w + (size_t)(mm * 17 + 16) * 1024;
                    f16x8 ah = *(const f16x8*)p, al = *(const f16x8*)(p + 512);
                    b2[mm][0] = MF(ah,bh,b2[mm][0]); b2[mm][0] = MF(ah,bl,b2[mm][0]); b2[mm][0] = MF(al,bh,b2[mm][0]);
                    b2[mm][1] = MF(ah,bh,b2[mm][1]); b2[mm][1] = MF(ah,bl,b2[mm][1]); b2[mm][1] = MF(al,bh,b2[mm][1]);
                }
            }
#pragma unroll
            for (int mm = 0; mm < 2; ++mm)
#pragma unroll
                for (int nt = 0; nt < 2; ++nt) {
                    float h2n = lstm_out(b2[mm][nt], c2[mm][nt]);
                    const int U = (2 * w + mm) * 4 + (l >> 4);      // local unit 0..63
                    const int ktl = U >> 5, ki = U & 31;
                    const int f = ((l & 15) + 16 * (ki >> 3)) * 8 + (ki & 7);
                    _Float16 hi = (_Float16)h2n;
                    hSt[((ktl*2+0)*2+nt)*512 + f] = hbits(hi);
                    hSt[((ktl*2+1)*2+nt)*512 + f] = hbits((_Float16)(h2n - (float)hi));
                }
        }
        __syncthreads();                          // hSt ready
        st4_sc((u32x4*)(Hb + hidx(bc, par) + uc * 4096) + t, ((const u32x4*)hSt)[t]);
        waitcnt0();
        __syncthreads();                          // slice stored
        if (t == 0) __hip_atomic_store(fptr(flags, bc, uc), s + 1,
                                       __ATOMIC_RELAXED, __HIP_MEMORY_SCOPE_AGENT);
    }

    // ============ Epilogue: head for step 59 ============
    if (t < 4) spin_ge(fptr(flags, bc, t), Tst);
    __syncthreads();
    stage32k(Hb + hidx(bc, (Tst - 1) & 1), Y, t);
    __syncthreads();
    {
        f32x4 pv = {0,0,0,0};
#pragma unroll
        for (int kt = 0; kt < 8; ++kt) {
            f16x8 bh = *(const f16x8*)&Y[((kt*2+0)*2+nth)*512 + l*8];
            f16x8 bl = *(const f16x8*)&Y[((kt*2+1)*2+nth)*512 + l*8];
            const u16* p = AHw + kt * 1024;
            f16x8 ah = *(const f16x8*)p, al = *(const f16x8*)(p + 512);
            pv = MF(ah, bh, pv); pv = MF(ah, bl, pv); pv = MF(al, bh, pv);
        }
        {
            f16x8 bh = *(const f16x8*)&onesF[l*8];
            f16x8 bl = *(const f16x8*)&onesF[512 + l*8];
            const u16* p = AHw + 8 * 1024;
            f16x8 ah = *(const f16x8*)p, al = *(const f16x8*)(p + 512);
            pv = MF(ah, bh, pv); pv = MF(ah, bl, pv); pv = MF(al, bh, pv);
        }
#pragma unroll
        for (int r = 0; r < 4; ++r) pv[r] = fmaxf(pv[r], 0.f);
        *(f32x4*)&mlpL[(nth * 16 + (l & 15)) * 68 + (w & 3) * 16 + (l >> 4) * 4] = pv;
    }
    __syncthreads();
    if (t < 256) {
        const int q = t >> 6, idx = t & 63, r = idx >> 1, o = idx & 1;
        float acc = 0.f;
#pragma unroll
        for (int k = 0; k < 16; ++k)
            acc = fmaf(mlpL[r * 68 + q * 16 + k], Wout2[o * 64 + q * 16 + k], acc);
        part[t] = acc;
    }
    __syncthreads();
    if (uc == 0 && t < 64) {
        const int r = t >> 1, o = t & 1;
        float acc = b_out2[o] + part[t] + part[64 + t] + part[128 + t] + part[192 + t];
        out[((size_t)(row0 + r) * Tst + (Tst - 1)) * 2 + o] = acc;
    }
}

// ---------------- launch ----------------
extern "C" void kernel_launch(void* const* d_in, const int* in_sizes, int n_in,
                              void* d_out, int out_size, void* d_ws, size_t ws_size,
                              hipStream_t stream) {
    const float* env   = (const float*)d_in[0];
    const float* hist  = (const float*)d_in[1];
    const float* goal  = (const float*)d_in[2];
    const float* cpos  = (const float*)d_in[3];
    const float* Wproj = (const float*)d_in[4];
    const float* bproj = (const float*)d_in[5];
    const float* Wih0  = (const float*)d_in[6];
    const float* Whh0  = (const float*)d_in[7];
    const float* bih0  = (const float*)d_in[8];
    const float* bhh0  = (const float*)d_in[9];
    const float* Wih1  = (const float*)d_in[10];
    const float* Whh1  = (const float*)d_in[11];
    const float* bih1  = (const float*)d_in[12];
    const float* bhh1  = (const float*)d_in[13];
    const float* Wout1 = (const float*)d_in[14];
    const float* bout1 = (const float*)d_in[15];
    const float* Wout2 = (const float*)d_in[16];
    const float* bout2 = (const float*)d_in[17];

    if (ws_size < WS_BYTES) return;
    u16* wsu = (u16*)d_ws;

    // flags must start at 0 each launch (no pre-main handshake needed:
    // step 0 is fully local; first spin at s=1 waits for step-0 stores)
    (void)hipMemsetAsync((char*)d_ws + (size_t)OFF_FLG * 2, 0x00,
                         (size_t)N_FLAGS_I * sizeof(int), stream);

    prep_kernel<<<(WS_U16 + 255) / 256, 256, 0, stream>>>(
        Wih0, Whh0, bih0, bhh0, Wih1, Whh1, bih1, bhh1, Wout1, bout1, wsu);

    lstm_main<<<256, 512, 0, stream>>>(
        env, hist, goal, cpos, Wproj, bproj, Wout2, bout2, wsu, (float*)d_out);
}

// Round 14
// 2000.291 us; speedup vs baseline: 3.1387x; 3.1387x over previous
//
#include <hip/hip_runtime.h>
#include <math.h>

using f16x8 = __attribute__((ext_vector_type(8))) _Float16;
using f32x4 = __attribute__((ext_vector_type(4))) float;
using u32x4 = __attribute__((ext_vector_type(4))) unsigned int;
using u16   = unsigned short;

// ---------------- problem constants ----------------
constexpr int Tst = 60;

// ---------------- workspace: A-fragment streams (layout identical to rounds 4-13) ----
constexpr int FR      = 512;
constexpr int N_AG0   = 64 * 9  * 2 * FR;
constexpr int N_AL0   = 64 * 9  * 2 * FR;
constexpr int N_AL1   = 64 * 17 * 2 * FR;
constexpr int N_AH1   = 4  * 9  * 2 * FR;
constexpr int OFF_AG0 = 0;
constexpr int OFF_AL0 = OFF_AG0 + N_AG0;
constexpr int OFF_AL1 = OFF_AL0 + N_AL0;
constexpr int OFF_AH1 = OFF_AL1 + N_AL1;
constexpr int WS_U16  = OFF_AH1 + N_AH1;          // 2,330,624 u16

// ---------------- h-exchange slabs + padded flags (identical to R9) ----------------
// H[bc 64][par 2][layer 2] slab of [kt 8][sb 2][nt 2][512] u16 = 32 KB
constexpr int N_HSLAB = 8 * 2 * 2 * 512;          // 16384 u16
constexpr int OFF_H   = WS_U16;
constexpr int N_H     = 64 * 2 * 2 * N_HSLAB;
constexpr int OFF_FLG = OFF_H + N_H;
constexpr int FLG_STRIDE = 32;                    // ints (128 B line per flag)
constexpr int N_FLAGS_I  = 64 * 2 * 4 * FLG_STRIDE;
constexpr size_t WS_BYTES = (size_t)OFF_FLG * 2 + (size_t)N_FLAGS_I * sizeof(int);

__device__ __forceinline__ u16 hbits(_Float16 h) {
    union { _Float16 h; u16 u; } x; x.h = h; return x.u;
}

// ---------------- weight repack (verbatim — validated rounds 4-13) ----------------
__global__ void prep_kernel(const float* __restrict__ Wih0, const float* __restrict__ Whh0,
                            const float* __restrict__ bih0, const float* __restrict__ bhh0,
                            const float* __restrict__ Wih1, const float* __restrict__ Whh1,
                            const float* __restrict__ bih1, const float* __restrict__ bhh1,
                            const float* __restrict__ Wout1, const float* __restrict__ bout1,
                            u16* __restrict__ ws) {
    int i = blockIdx.x * 256 + threadIdx.x;
    if (i >= WS_U16) return;
    int arr, idx = i, KT;
    if (i < OFF_AL0)      { arr = 0; KT = 9; }
    else if (i < OFF_AL1) { arr = 1; idx -= OFF_AL0; KT = 9; }
    else if (i < OFF_AH1) { arr = 2; idx -= OFF_AL1; KT = 17; }
    else                  { arr = 3; idx -= OFF_AH1; KT = 9; }
    const int per_mt = KT * 2 * FR;
    const int mt = idx / per_mt;
    int r = idx - mt * per_mt;
    const int kt = r / (2 * FR);
    r -= kt * 2 * FR;
    const int s    = r >> 9;
    const int f    = r & 511;
    const int lane = f >> 3, j = f & 7;
    const int m    = mt * 16 + (lane & 15);
    const int k_in = ((lane >> 4) << 3) + j;

    float v = 0.f;
    if (arr == 3) {
        if (kt < 8) v = Wout1[m * 256 + kt * 32 + k_in];
        else if (k_in == 0) v = bout1[m];
    } else {
        const int unit = m >> 2, gate = m & 3, row = gate * 256 + unit;
        if (arr == 0) {
            if (kt < 8) v = Wih0[row * 258 + 2 + kt * 32 + k_in];
            else if (k_in == 0) v = bih0[row] + bhh0[row];
        } else if (arr == 1) {
            if (kt < 8) v = Whh0[row * 256 + kt * 32 + k_in];
            else if (k_in < 2) v = Wih0[row * 258 + k_in];
        } else {
            if (kt < 8)         v = Wih1[row * 256 + kt * 32 + k_in];
            else if (kt < 16)   v = Whh1[row * 256 + (kt - 8) * 32 + k_in];
            else if (k_in == 0) v = bih1[row] + bhh1[row];
        }
    }
    _Float16 hi = (_Float16)v;
    ws[i] = (s == 0) ? hbits(hi) : hbits((_Float16)(v - (float)hi));
}

// ---------------- helpers ----------------
__device__ __forceinline__ f32x4 MF(f16x8 a, f16x8 b, f32x4 c) {
    return __builtin_amdgcn_mfma_f32_16x16x32_f16(a, b, c, 0, 0, 0);
}
__device__ __forceinline__ float sigm(float x) { return 1.f / (1.f + __expf(-x)); }
__device__ __forceinline__ float tanh_(float x) {
    float e = __expf(-2.f * fabsf(x));
    float r = (1.f - e) / (1.f + e);
    return copysignf(r, x);
}
__device__ __forceinline__ float lstm_out(f32x4 g, float& c) {
    float iv = sigm(g[0]), fv = sigm(g[1]), gv = tanh_(g[2]), ov = sigm(g[3]);
    c = fmaf(fv, c, iv * gv);
    return ov * tanh_(c);
}
__device__ __forceinline__ void waitcnt0() {
    asm volatile("s_waitcnt vmcnt(0)" ::: "memory");
}
__device__ __forceinline__ void st16_sc(u16* p, u16 v) {
    asm volatile("global_store_short %0, %1, off sc0 sc1" :: "v"(p), "v"((unsigned)v) : "memory");
}
__device__ __forceinline__ void ld4_sc(const u32x4* p, u32x4& v) {
    asm volatile("global_load_dwordx4 %0, %1, off sc0 sc1" : "=v"(v) : "v"(p));
}
__device__ __forceinline__ void st4_sc(u32x4* p, u32x4 v) {
    asm volatile("global_store_dwordx4 %0, %1, off sc0 sc1" :: "v"(p), "v"(v) : "memory");
}
// 32 KB coherent global->LDS stage; 1024 threads x 2 x 16B
__device__ __forceinline__ void stage32k(const u16* g, u16* lds, int t) {
    const u32x4* s = (const u32x4*)g;
    u32x4 v0, v1;
    ld4_sc(s + t, v0); ld4_sc(s + t + 1024, v1);
    waitcnt0();
    __builtin_amdgcn_sched_barrier(0);
    u32x4* d = (u32x4*)lds;
    d[t] = v0; d[t + 1024] = v1;
}
__device__ __forceinline__ void spin_ge(int* p, int target) {
    while (__hip_atomic_load(p, __ATOMIC_RELAXED, __HIP_MEMORY_SCOPE_AGENT) < target)
        __builtin_amdgcn_s_sleep(1);
}
__device__ __forceinline__ size_t hidx(int bc, int par, int layer) {
    return (size_t)((bc * 2 + par) * 2 + layer) * N_HSLAB;
}
__device__ __forceinline__ int* fptr(int* flags, int bc, int layer, int uc) {
    return flags + (size_t)((bc * 2 + layer) * 4 + uc) * FLG_STRIDE;
}

// ---------------- main kernel: 256 blocks = 64 bc x 4 uc, 1024 thr = 16 waves ----
// R9 structure (retained X=h1, Y=h2; weight-sliced uc partition, validated) with
// phase C merged into the NEXT step's phase A: the fB spin + Y stage + head(s-1)
// sit AFTER the dependency-free L0 kt0-7 MFMA block, hiding partner skew.
// 2 phases/step: A' {L0 local | spin fB, stage Y, head | pos, store h1, fA},
//                B  {Y-part | spin fA, stage X | X-part, store h2, fB}.
__global__ __launch_bounds__(1024) void lstm_main(
    const float* __restrict__ env, const float* __restrict__ hist,
    const float* __restrict__ goal, const float* __restrict__ cpos,
    const float* __restrict__ Wproj, const float* __restrict__ b_proj,
    const float* __restrict__ Wout2, const float* __restrict__ b_out2,
    u16* __restrict__ wsu, float* __restrict__ out) {

    __shared__ __align__(16) unsigned char smem[89600];
    u16*   X    = (u16*)smem;                     // 32 KB (retained h1)
    u16*   Y    = (u16*)(smem + 32768);           // 32 KB (retained h2)
    u16*   hSt  = (u16*)(smem + 65536);           // 8 KB own-slice coalesce
    float* mlpL = (float*)(smem + 73728);         // [32][68] f32 = 8704 B
    float* part = (float*)(smem + 82432);         // [256] f32 = 1024 B
    u16*   posF = (u16*)(smem + 83456);           // [sb2][nt2][512] = 4 KB
    u16*   onesF= (u16*)(smem + 87552);           // [sb2][512] = 2 KB
    float* xbuf = (float*)smem;                   // prologue overlay [386][32]
    float* ctxL = (float*)(smem + 49408);         // prologue overlay [256][32]

    const int t  = threadIdx.x;
    const int w  = t >> 6;                        // 0..15
    const int l  = t & 63;
    const int bc = (int)blockIdx.x >> 2;
    const int uc = (int)blockIdx.x & 3;           // one uc per XCD -> weights L2-resident
    const int row0 = bc * 32;

    u16* Hb = wsu + OFF_H;
    int* flags = (int*)(wsu + OFF_FLG);

    const u16* AG0w = wsu + OFF_AG0 + (size_t)(uc * 16 + w) * (9 * 1024)  + l * 8;
    const u16* A0w  = wsu + OFF_AL0 + (size_t)(uc * 16 + w) * (9 * 1024)  + l * 8;
    const u16* A1w  = wsu + OFF_AL1 + (size_t)(uc * 16 + w) * (17 * 1024) + l * 8;
    const u16* AHw  = wsu + OFF_AH1 + (size_t)(w & 3) * (9 * 1024) + l * 8;
    const int  nth  = w >> 2;                     // head nt (waves 0..7 only)

    // ---- P1: stage ctx_in [k][r] ----
    for (int idx = t; idx < 386 * 32; idx += 1024) {
        int r = idx & 31, k = idx >> 5;
        int gr = row0 + r; float v;
        if (k < 256)      v = env[gr * 256 + k];
        else if (k < 384) v = hist[gr * 128 + (k - 256)];
        else              v = goal[gr * 2 + (k - 384)];
        xbuf[k * 32 + r] = v;
    }
    __syncthreads();

    // ---- P2: context fp32 (256 units x 32 rows; thread = (u, 8-row chunk)) ----
    {
        const int u = t & 255, rh = t >> 8;       // rh 0..3
        float acc[8];
        float bp = b_proj[u];
#pragma unroll
        for (int rr = 0; rr < 8; ++rr) acc[rr] = bp;
        for (int k = 0; k < 386; ++k) {
            float wv = Wproj[u * 386 + k];
            const float* xr = &xbuf[k * 32 + rh * 8];
#pragma unroll
            for (int rr = 0; rr < 8; ++rr) acc[rr] = fmaf(xr[rr], wv, acc[rr]);
        }
#pragma unroll
        for (int rr = 0; rr < 8; ++rr) ctxL[u * 32 + rh * 8 + rr] = acc[rr];
    }
    __syncthreads();

    // ---- P3: write own uc-slice of h1(-1), h2(-1) slabs (parity 1) ----
    for (int idx = t; idx < 8192; idx += 1024) {
        int layer = idx >> 12;
        int j2 = idx & 4095;
        int f = j2 & 511, nt = (j2 >> 9) & 1, sb = (j2 >> 10) & 1, kl = j2 >> 11;
        int lane = f >> 3, j = f & 7;
        int k_in = ((lane >> 4) << 3) + j;
        int Ug = uc * 64 + kl * 32 + k_in;
        float v = ctxL[Ug * 32 + nt * 16 + (lane & 15)];
        _Float16 hi = (_Float16)v;
        u16 val = sb ? hbits((_Float16)(v - (float)hi)) : hbits(hi);
        int kt = uc * 2 + kl;
        st16_sc(Hb + hidx(bc, 1, layer) + ((kt * 2 + sb) * 2 + nt) * 512 + f, val);
    }
    waitcnt0();
    __syncthreads();
    if (t == 0) {
        __hip_atomic_store(fptr(flags, bc, 1, uc), 0, __ATOMIC_RELAXED, __HIP_MEMORY_SCOPE_AGENT);
        __hip_atomic_store(fptr(flags, bc, 0, uc), 0, __ATOMIC_RELAXED, __HIP_MEMORY_SCOPE_AGENT);
    }
    __syncthreads();

    // ---- P4: posF + onesF ----
    for (int idx = t; idx < 2048; idx += 1024) {
        int f = idx & 511, nt = (idx >> 9) & 1, sb = idx >> 10;
        int lane = f >> 3, j = f & 7;
        int k_in = ((lane >> 4) << 3) + j;
        u16 val = 0;
        if (k_in < 2) {
            float pv = cpos[(row0 + nt * 16 + (lane & 15)) * 2 + k_in];
            _Float16 hi = (_Float16)pv;
            val = sb ? hbits((_Float16)(pv - (float)hi)) : hbits(hi);
        }
        posF[(sb * 2 + nt) * 512 + f] = val;
    }
    if (t < 1024) {
        int f = t & 511, sb = t >> 9;
        int lane = f >> 3, j = f & 7;
        int k_in = ((lane >> 4) << 3) + j;
        onesF[sb * 512 + f] = (sb == 0 && k_in == 0) ? hbits((_Float16)1.0f) : (u16)0;
    }
    __syncthreads();

    // ---- P5a: stage X = h1(-1); G0c via MFMA ----
    if (t < 4) spin_ge(fptr(flags, bc, 0, t), 0);
    __syncthreads();
    stage32k(Hb + hidx(bc, 1, 0), X, t);
    __syncthreads();

    f32x4 G00 = {0,0,0,0}, G01 = {0,0,0,0};
#pragma unroll
    for (int kt = 0; kt < 8; ++kt) {
        f16x8 bh0 = *(const f16x8*)&X[((kt*2+0)*2+0)*512 + l*8];
        f16x8 bh1 = *(const f16x8*)&X[((kt*2+0)*2+1)*512 + l*8];
        f16x8 bl0 = *(const f16x8*)&X[((kt*2+1)*2+0)*512 + l*8];
        f16x8 bl1 = *(const f16x8*)&X[((kt*2+1)*2+1)*512 + l*8];
        const u16* p = AG0w + kt * 1024;
        f16x8 ah = *(const f16x8*)p, al = *(const f16x8*)(p + 512);
        G00 = MF(ah,bh0,G00); G00 = MF(ah,bl0,G00); G00 = MF(al,bh0,G00);
        G01 = MF(ah,bh1,G01); G01 = MF(ah,bl1,G01); G01 = MF(al,bh1,G01);
    }
    {
        f16x8 bh = *(const f16x8*)&onesF[l*8];
        f16x8 bl = *(const f16x8*)&onesF[512 + l*8];
        const u16* p = AG0w + 8 * 1024;
        f16x8 ah = *(const f16x8*)p, al = *(const f16x8*)(p + 512);
        G00 = MF(ah,bh,G00); G00 = MF(ah,bl,G00); G00 = MF(al,bh,G00);
        G01 = MF(ah,bh,G01); G01 = MF(ah,bl,G01); G01 = MF(al,bh,G01);
    }

    // ---- P5b: stage Y = h2(-1) ----
    if (t < 4) spin_ge(fptr(flags, bc, 1, t), 0);
    __syncthreads();
    stage32k(Hb + hidx(bc, 1, 1), Y, t);
    __syncthreads();

    float c1[2] = {0,0}, c2[2] = {0,0};

    // ================= time loop (2 phases/step) =================
    for (int s = 0; s < Tst; ++s) {
        const int par = s & 1;

        // ===== Phase A': L0 kt0-7 (local, hides fB spin) =====
        f32x4 a0 = G00, a1 = G01;
#pragma unroll
        for (int kt = 0; kt < 8; ++kt) {
            f16x8 bh0 = *(const f16x8*)&X[((kt*2+0)*2+0)*512 + l*8];
            f16x8 bh1 = *(const f16x8*)&X[((kt*2+0)*2+1)*512 + l*8];
            f16x8 bl0 = *(const f16x8*)&X[((kt*2+1)*2+0)*512 + l*8];
            f16x8 bl1 = *(const f16x8*)&X[((kt*2+1)*2+1)*512 + l*8];
            const u16* p = A0w + kt * 1024;
            f16x8 ah = *(const f16x8*)p, al = *(const f16x8*)(p + 512);
            a0 = MF(ah,bh0,a0); a0 = MF(ah,bl0,a0); a0 = MF(al,bh0,a0);
            a1 = MF(ah,bh1,a1); a1 = MF(ah,bl1,a1); a1 = MF(al,bh1,a1);
        }

        // ---- merged old-phase-C: stage Y = h2(s-1), head(s-1) -> out, posF(s) ----
        if (s >= 1) {
            if (t < 4) spin_ge(fptr(flags, bc, 1, t), s);      // h2(s-1) stores done
            __syncthreads();                                   // spin seen; Y reads of B(s-1) done
            stage32k(Hb + hidx(bc, par ^ 1, 1), Y, t);         // Y <- h2(s-1), retained for B(s)
            __syncthreads();
            if (w < 8) {                                       // head MFMA
                f32x4 pv = {0,0,0,0};
#pragma unroll
                for (int kt = 0; kt < 8; ++kt) {
                    f16x8 bh = *(const f16x8*)&Y[((kt*2+0)*2+nth)*512 + l*8];
                    f16x8 bl = *(const f16x8*)&Y[((kt*2+1)*2+nth)*512 + l*8];
                    const u16* p = AHw + kt * 1024;
                    f16x8 ah = *(const f16x8*)p, al = *(const f16x8*)(p + 512);
                    pv = MF(ah, bh, pv); pv = MF(ah, bl, pv); pv = MF(al, bh, pv);
                }
                {
                    f16x8 bh = *(const f16x8*)&onesF[l*8];
                    f16x8 bl = *(const f16x8*)&onesF[512 + l*8];
                    const u16* p = AHw + 8 * 1024;
                    f16x8 ah = *(const f16x8*)p, al = *(const f16x8*)(p + 512);
                    pv = MF(ah, bh, pv); pv = MF(ah, bl, pv); pv = MF(al, bh, pv);
                }
#pragma unroll
                for (int r = 0; r < 4; ++r) pv[r] = fmaxf(pv[r], 0.f);
                *(f32x4*)&mlpL[(nth * 16 + (l & 15)) * 68 + (w & 3) * 16 + (l >> 4) * 4] = pv;
            }
            __syncthreads();                                   // mlpL ready
            if (t < 256) {                                     // head2 partials (q4, r32, o2)
                const int q = t >> 6, idx = t & 63, r = idx >> 1, o = idx & 1;
                float acc = 0.f;
#pragma unroll
                for (int k = 0; k < 16; ++k)
                    acc = fmaf(mlpL[r * 68 + q * 16 + k], Wout2[o * 64 + q * 16 + k], acc);
                part[t] = acc;
            }
            __syncthreads();
            if (t < 64) {
                const int r = t >> 1, o = t & 1;
                float acc = b_out2[o] + part[t] + part[64 + t] + part[128 + t] + part[192 + t];
                if (uc == 0) out[((size_t)(row0 + r) * Tst + (s - 1)) * 2 + o] = acc;
                _Float16 hi = (_Float16)acc;
                posF[(0 * 2 + (r >> 4)) * 512 + (r & 15) * 8 + o] = hbits(hi);
                posF[(2 + (r >> 4)) * 512 + (r & 15) * 8 + o] = hbits((_Float16)(acc - (float)hi));
            }
            __syncthreads();                                   // posF(s) ready
        }

        // ---- pos column (kt 8) + lstm_out -> h1(s) slice ----
        {
            f16x8 bh0 = *(const f16x8*)&posF[(0*2+0)*512 + l*8];
            f16x8 bh1 = *(const f16x8*)&posF[(0*2+1)*512 + l*8];
            f16x8 bl0 = *(const f16x8*)&posF[(1*2+0)*512 + l*8];
            f16x8 bl1 = *(const f16x8*)&posF[(1*2+1)*512 + l*8];
            const u16* p = A0w + 8 * 1024;
            f16x8 ah = *(const f16x8*)p, al = *(const f16x8*)(p + 512);
            a0 = MF(ah,bh0,a0); a0 = MF(ah,bl0,a0); a0 = MF(al,bh0,a0);
            a1 = MF(ah,bh1,a1); a1 = MF(ah,bl1,a1); a1 = MF(al,bh1,a1);
        }
        {
            float h1n[2];
            h1n[0] = lstm_out(a0, c1[0]);
            h1n[1] = lstm_out(a1, c1[1]);
            const int U   = w * 4 + (l >> 4);
            const int ktl = U >> 5, ki = U & 31;
            const int f   = ((l & 15) + 16 * (ki >> 3)) * 8 + (ki & 7);
#pragma unroll
            for (int nt = 0; nt < 2; ++nt) {
                float v = h1n[nt];
                _Float16 hi = (_Float16)v;
                hSt[((ktl*2+0)*2+nt)*512 + f] = hbits(hi);
                hSt[((ktl*2+1)*2+nt)*512 + f] = hbits((_Float16)(v - (float)hi));
            }
        }
        __syncthreads();                                       // hSt ready
        if (t < 512) st4_sc((u32x4*)(Hb + hidx(bc, par, 0) + uc * 4096) + t, ((const u32x4*)hSt)[t]);
        waitcnt0();
        __syncthreads();                                       // slice stored
        if (t == 0) __hip_atomic_store(fptr(flags, bc, 0, uc), s + 1,
                                       __ATOMIC_RELAXED, __HIP_MEMORY_SCOPE_AGENT);

        // ===== Phase B: Y-part first (retained, no deps); spin fA; stage X; X-part =====
        a0 = f32x4{0,0,0,0}; a1 = f32x4{0,0,0,0};
#pragma unroll
        for (int ks = 0; ks < 8; ++ks) {                       // Whh1 @ h2(s-1) (retained Y)
            f16x8 bh0 = *(const f16x8*)&Y[((ks*2+0)*2+0)*512 + l*8];
            f16x8 bh1 = *(const f16x8*)&Y[((ks*2+0)*2+1)*512 + l*8];
            f16x8 bl0 = *(const f16x8*)&Y[((ks*2+1)*2+0)*512 + l*8];
            f16x8 bl1 = *(const f16x8*)&Y[((ks*2+1)*2+1)*512 + l*8];
            const u16* p = A1w + (8 + ks) * 1024;
            f16x8 ah = *(const f16x8*)p, al = *(const f16x8*)(p + 512);
            a0 = MF(ah,bh0,a0); a0 = MF(ah,bl0,a0); a0 = MF(al,bh0,a0);
            a1 = MF(ah,bh1,a1); a1 = MF(ah,bl1,a1); a1 = MF(al,bh1,a1);
        }
        {   // bias column (kt 16)
            f16x8 bh = *(const f16x8*)&onesF[l*8];
            f16x8 bl = *(const f16x8*)&onesF[512 + l*8];
            const u16* p = A1w + 16 * 1024;
            f16x8 ah = *(const f16x8*)p, al = *(const f16x8*)(p + 512);
            a0 = MF(ah,bh,a0); a0 = MF(ah,bl,a0); a0 = MF(al,bh,a0);
            a1 = MF(ah,bh,a1); a1 = MF(ah,bl,a1); a1 = MF(al,bh,a1);
        }
        if (t < 4) spin_ge(fptr(flags, bc, 0, t), s + 1);      // h1(s) full
        __syncthreads();
        stage32k(Hb + hidx(bc, par, 0), X, t);                 // X <- h1(s), retained for A'(s+1)
        __syncthreads();
#pragma unroll
        for (int kt = 0; kt < 8; ++kt) {                       // Wih1 @ h1(s)
            f16x8 bh0 = *(const f16x8*)&X[((kt*2+0)*2+0)*512 + l*8];
            f16x8 bh1 = *(const f16x8*)&X[((kt*2+0)*2+1)*512 + l*8];
            f16x8 bl0 = *(const f16x8*)&X[((kt*2+1)*2+0)*512 + l*8];
            f16x8 bl1 = *(const f16x8*)&X[((kt*2+1)*2+1)*512 + l*8];
            const u16* p = A1w + kt * 1024;
            f16x8 ah = *(const f16x8*)p, al = *(const f16x8*)(p + 512);
            a0 = MF(ah,bh0,a0); a0 = MF(ah,bl0,a0); a0 = MF(al,bh0,a0);
            a1 = MF(ah,bh1,a1); a1 = MF(ah,bl1,a1); a1 = MF(al,bh1,a1);
        }
        {
            float h2n[2];
            h2n[0] = lstm_out(a0, c2[0]);
            h2n[1] = lstm_out(a1, c2[1]);
            const int U   = w * 4 + (l >> 4);
            const int ktl = U >> 5, ki = U & 31;
            const int f   = ((l & 15) + 16 * (ki >> 3)) * 8 + (ki & 7);
#pragma unroll
            for (int nt = 0; nt < 2; ++nt) {
                float v = h2n[nt];
                _Float16 hi = (_Float16)v;
                hSt[((ktl*2+0)*2+nt)*512 + f] = hbits(hi);
                hSt[((ktl*2+1)*2+nt)*512 + f] = hbits((_Float16)(v - (float)hi));
            }
        }
        __syncthreads();                                       // hSt ready
        if (t < 512) st4_sc((u32x4*)(Hb + hidx(bc, par, 1) + uc * 4096) + t, ((const u32x4*)hSt)[t]);
        waitcnt0();
        __syncthreads();                                       // slice stored
        if (t == 0) __hip_atomic_store(fptr(flags, bc, 1, uc), s + 1,
                                       __ATOMIC_RELAXED, __HIP_MEMORY_SCOPE_AGENT);
    }

    // ============ Epilogue: head for step 59 ============
    if (t < 4) spin_ge(fptr(flags, bc, 1, t), Tst);
    __syncthreads();
    stage32k(Hb + hidx(bc, (Tst - 1) & 1, 1), Y, t);
    __syncthreads();
    if (w < 8) {
        f32x4 pv = {0,0,0,0};
#pragma unroll
        for (int kt = 0; kt < 8; ++kt) {
            f16x8 bh = *(const f16x8*)&Y[((kt*2+0)*2+nth)*512 + l*8];
            f16x8 bl = *(const f16x8*)&Y[((kt*2+1)*2+nth)*512 + l*8];
            const u16* p = AHw + kt * 1024;
            f16x8 ah = *(const f16x8*)p, al = *(const f16x8*)(p + 512);
            pv = MF(ah, bh, pv); pv = MF(ah, bl, pv); pv = MF(al, bh, pv);
        }
        {
            f16x8 bh = *(const f16x8*)&onesF[l*8];
            f16x8 bl = *(const f16x8*)&onesF[512 + l*8];
            const u16* p = AHw + 8 * 1024;
            f16x8 ah = *(const f16x8*)p, al = *(const f16x8*)(p + 512);
            pv = MF(ah, bh, pv); pv = MF(ah, bl, pv); pv = MF(al, bh, pv);
        }
#pragma unroll
        for (int r = 0; r < 4; ++r) pv[r] = fmaxf(pv[r], 0.f);
        *(f32x4*)&mlpL[(nth * 16 + (l & 15)) * 68 + (w & 3) * 16 + (l >> 4) * 4] = pv;
    }
    __syncthreads();
    if (t < 256) {
        const int q = t >> 6, idx = t & 63, r = idx >> 1, o = idx & 1;
        float acc = 0.f;
#pragma unroll
        for (int k = 0; k < 16; ++k)
            acc = fmaf(mlpL[r * 68 + q * 16 + k], Wout2[o * 64 + q * 16 + k], acc);
        part[t] = acc;
    }
    __syncthreads();
    if (uc == 0 && t < 64) {
        const int r = t >> 1, o = t & 1;
        float acc = b_out2[o] + part[t] + part[64 + t] + part[128 + t] + part[192 + t];
        out[((size_t)(row0 + r) * Tst + (Tst - 1)) * 2 + o] = acc;
    }
}

// ---------------- launch ----------------
extern "C" void kernel_launch(void* const* d_in, const int* in_sizes, int n_in,
                              void* d_out, int out_size, void* d_ws, size_t ws_size,
                              hipStream_t stream) {
    const float* env   = (const float*)d_in[0];
    const float* hist  = (const float*)d_in[1];
    const float* goal  = (const float*)d_in[2];
    const float* cpos  = (const float*)d_in[3];
    const float* Wproj = (const float*)d_in[4];
    const float* bproj = (const float*)d_in[5];
    const float* Wih0  = (const float*)d_in[6];
    const float* Whh0  = (const float*)d_in[7];
    const float* bih0  = (const float*)d_in[8];
    const float* bhh0  = (const float*)d_in[9];
    const float* Wih1  = (const float*)d_in[10];
    const float* Whh1  = (const float*)d_in[11];
    const float* bih1  = (const float*)d_in[12];
    const float* bhh1  = (const float*)d_in[13];
    const float* Wout1 = (const float*)d_in[14];
    const float* bout1 = (const float*)d_in[15];
    const float* Wout2 = (const float*)d_in[16];
    const float* bout2 = (const float*)d_in[17];

    if (ws_size < WS_BYTES) return;
    u16* wsu = (u16*)d_ws;

    (void)hipMemsetAsync((char*)d_ws + (size_t)OFF_FLG * 2, 0xFF,
                         (size_t)N_FLAGS_I * sizeof(int), stream);

    prep_kernel<<<(WS_U16 + 255) / 256, 256, 0, stream>>>(
        Wih0, Whh0, bih0, bhh0, Wih1, Whh1, bih1, bhh1, Wout1, bout1, wsu);

    lstm_main<<<256, 1024, 0, stream>>>(
        env, hist, goal, cpos, Wproj, bproj, Wout2, bout2, wsu, (float*)d_out);
}

// Round 16
// 1835.699 us; speedup vs baseline: 3.4201x; 1.0897x over previous
//
#include <hip/hip_runtime.h>
#include <math.h>

using f16x8 = __attribute__((ext_vector_type(8))) _Float16;
using f32x4 = __attribute__((ext_vector_type(4))) float;
using u32x4 = __attribute__((ext_vector_type(4))) unsigned int;
using u16   = unsigned short;

// ---------------- problem constants ----------------
constexpr int Tst = 60;

// ---------------- workspace: A-fragment streams (layout identical to rounds 4-8) ----
constexpr int FR      = 512;
constexpr int N_AG0   = 64 * 9  * 2 * FR;
constexpr int N_AL0   = 64 * 9  * 2 * FR;
constexpr int N_AL1   = 64 * 17 * 2 * FR;
constexpr int N_AH1   = 4  * 9  * 2 * FR;
constexpr int OFF_AG0 = 0;
constexpr int OFF_AL0 = OFF_AG0 + N_AG0;
constexpr int OFF_AL1 = OFF_AL0 + N_AL0;
constexpr int OFF_AH1 = OFF_AL1 + N_AL1;
constexpr int WS_U16  = OFF_AH1 + N_AH1;          // 2,330,624 u16

// ---------------- h-exchange slabs + padded flags ----------------
// H[bc 64][par 2][layer 2] slab of [kt 8][s 2][nt 2][512] u16
constexpr int N_HSLAB = 8 * 2 * 2 * 512;          // 16384 u16 = 32 KB
constexpr int OFF_H   = WS_U16;
constexpr int N_H     = 64 * 2 * 2 * N_HSLAB;
constexpr int OFF_FLG = OFF_H + N_H;              // flags (int), one per 128B line
constexpr int FLG_STRIDE = 32;                    // ints (128 B)
constexpr int N_FLAGS_I  = 64 * 2 * 4 * FLG_STRIDE;   // 16384 ints = 64 KB
constexpr size_t WS_BYTES = (size_t)OFF_FLG * 2 + (size_t)N_FLAGS_I * sizeof(int);

__device__ __forceinline__ u16 hbits(_Float16 h) {
    union { _Float16 h; u16 u; } x; x.h = h; return x.u;
}

// ---------------- weight repack (verbatim — validated rounds 4-9) ----------------
__global__ void prep_kernel(const float* __restrict__ Wih0, const float* __restrict__ Whh0,
                            const float* __restrict__ bih0, const float* __restrict__ bhh0,
                            const float* __restrict__ Wih1, const float* __restrict__ Whh1,
                            const float* __restrict__ bih1, const float* __restrict__ bhh1,
                            const float* __restrict__ Wout1, const float* __restrict__ bout1,
                            u16* __restrict__ ws) {
    int i = blockIdx.x * 256 + threadIdx.x;
    if (i >= WS_U16) return;
    int arr, idx = i, KT;
    if (i < OFF_AL0)      { arr = 0; KT = 9; }
    else if (i < OFF_AL1) { arr = 1; idx -= OFF_AL0; KT = 9; }
    else if (i < OFF_AH1) { arr = 2; idx -= OFF_AL1; KT = 17; }
    else                  { arr = 3; idx -= OFF_AH1; KT = 9; }
    const int per_mt = KT * 2 * FR;
    const int mt = idx / per_mt;
    int r = idx - mt * per_mt;
    const int kt = r / (2 * FR);
    r -= kt * 2 * FR;
    const int s    = r >> 9;
    const int f    = r & 511;
    const int lane = f >> 3, j = f & 7;
    const int m    = mt * 16 + (lane & 15);
    const int k_in = ((lane >> 4) << 3) + j;

    float v = 0.f;
    if (arr == 3) {
        if (kt < 8) v = Wout1[m * 256 + kt * 32 + k_in];
        else if (k_in == 0) v = bout1[m];
    } else {
        const int unit = m >> 2, gate = m & 3, row = gate * 256 + unit;
        if (arr == 0) {
            if (kt < 8) v = Wih0[row * 258 + 2 + kt * 32 + k_in];
            else if (k_in == 0) v = bih0[row] + bhh0[row];
        } else if (arr == 1) {
            if (kt < 8) v = Whh0[row * 256 + kt * 32 + k_in];
            else if (k_in < 2) v = Wih0[row * 258 + k_in];
        } else {
            if (kt < 8)         v = Wih1[row * 256 + kt * 32 + k_in];
            else if (kt < 16)   v = Whh1[row * 256 + (kt - 8) * 32 + k_in];
            else if (k_in == 0) v = bih1[row] + bhh1[row];
        }
    }
    _Float16 hi = (_Float16)v;
    ws[i] = (s == 0) ? hbits(hi) : hbits((_Float16)(v - (float)hi));
}

// ---------------- helpers ----------------
__device__ __forceinline__ f32x4 MF(f16x8 a, f16x8 b, f32x4 c) {
    return __builtin_amdgcn_mfma_f32_16x16x32_f16(a, b, c, 0, 0, 0);
}
__device__ __forceinline__ float sigm(float x) { return 1.f / (1.f + __expf(-x)); }
__device__ __forceinline__ float tanh_(float x) {
    float e = __expf(-2.f * fabsf(x));
    float r = (1.f - e) / (1.f + e);
    return copysignf(r, x);
}
__device__ __forceinline__ float lstm_out(f32x4 g, float& c) {
    float iv = sigm(g[0]), fv = sigm(g[1]), gv = tanh_(g[2]), ov = sigm(g[3]);
    c = fmaf(fv, c, iv * gv);
    return ov * tanh_(c);
}
__device__ __forceinline__ void waitcnt0() {
    asm volatile("s_waitcnt vmcnt(0)" ::: "memory");
}
__device__ __forceinline__ void st16_sc(u16* p, u16 v) {
    asm volatile("global_store_short %0, %1, off sc0 sc1" :: "v"(p), "v"((unsigned)v) : "memory");
}
__device__ __forceinline__ void ld4_sc(const u32x4* p, u32x4& v) {
    asm volatile("global_load_dwordx4 %0, %1, off sc0 sc1" : "=v"(v) : "v"(p));
}
__device__ __forceinline__ void st4_sc(u32x4* p, u32x4 v) {
    asm volatile("global_store_dwordx4 %0, %1, off sc0 sc1" :: "v"(p), "v"(v) : "memory");
}
// 32 KB coherent global->LDS stage; 1024 threads x 2 x 16B
__device__ __forceinline__ void stage32k(const u16* g, u16* lds, int t) {
    const u32x4* s = (const u32x4*)g;
    u32x4 v0, v1;
    ld4_sc(s + t, v0); ld4_sc(s + t + 1024, v1);
    waitcnt0();
    __builtin_amdgcn_sched_barrier(0);
    u32x4* d = (u32x4*)lds;
    d[t] = v0; d[t + 1024] = v1;
}
__device__ __forceinline__ void spin_ge(int* p, int target) {
    while (__hip_atomic_load(p, __ATOMIC_RELAXED, __HIP_MEMORY_SCOPE_AGENT) < target)
        __builtin_amdgcn_s_sleep(1);
}
__device__ __forceinline__ size_t hidx(int bc, int par, int layer) {
    return (size_t)((bc * 2 + par) * 2 + layer) * N_HSLAB;
}
__device__ __forceinline__ int* fptr(int* flags, int bc, int layer, int uc) {
    return flags + (size_t)((bc * 2 + layer) * 4 + uc) * FLG_STRIDE;
}

// ---------------- main kernel: 256 blocks = 64 bc x 4 uc, 1024 thr = 16 waves ----
// wave w owns M-tile (uc*16 + w): units [uc*64 + 4w, uc*64 + 4w + 4)
// Retained LDS buffers: X = h1 (staged once per step, in B), Y = h2 (staged once, in C).
// Phase A is pure local compute (reuses X from previous B-stage).
__global__ __launch_bounds__(1024) void lstm_main(
    const float* __restrict__ env, const float* __restrict__ hist,
    const float* __restrict__ goal, const float* __restrict__ cpos,
    const float* __restrict__ Wproj, const float* __restrict__ b_proj,
    const float* __restrict__ Wout2, const float* __restrict__ b_out2,
    u16* __restrict__ wsu, float* __restrict__ out) {

    __shared__ __align__(16) unsigned char smem[90112];
    u16*   X    = (u16*)smem;                     // 32 KB (retained h1)
    u16*   Y    = (u16*)(smem + 32768);           // 32 KB (retained h2)
    u16*   hSt  = (u16*)(smem + 65536);           // 8 KB: own h-slice (coalesce)
    float* mlpL = (float*)(smem + 73728);         // [32][68] f32 (ends 82432)
    u16*   posF = (u16*)(smem + 82944);           // [s2][nt2][512]
    u16*   onesF= (u16*)(smem + 87040);           // [s2][512]
    float* xbuf = (float*)smem;                   // prologue overlay [386][32]
    float* ctxL = (float*)(smem + 49408);         // prologue overlay [256][32]

    const int t  = threadIdx.x;
    const int w  = t >> 6;                        // 0..15
    const int l  = t & 63;
    const int bc = (int)blockIdx.x >> 2;
    const int uc = (int)blockIdx.x & 3;           // one uc per XCD -> weights L2-resident
    const int row0 = bc * 32;

    u16* Hb = wsu + OFF_H;
    int* flags = (int*)(wsu + OFF_FLG);

    const u16* AG0w = wsu + OFF_AG0 + (size_t)(uc * 16 + w) * (9 * 1024)  + l * 8;
    const u16* A0w  = wsu + OFF_AL0 + (size_t)(uc * 16 + w) * (9 * 1024)  + l * 8;
    const u16* A1w  = wsu + OFF_AL1 + (size_t)(uc * 16 + w) * (17 * 1024) + l * 8;
    const u16* AHw  = wsu + OFF_AH1 + (size_t)(w & 3) * (9 * 1024) + l * 8;
    const int  nth  = w >> 2;                     // head nt (waves 0..7 only)

    // ---- P1: stage ctx_in [k][r] ----
    for (int idx = t; idx < 386 * 32; idx += 1024) {
        int r = idx & 31, k = idx >> 5;
        int gr = row0 + r; float v;
        if (k < 256)      v = env[gr * 256 + k];
        else if (k < 384) v = hist[gr * 128 + (k - 256)];
        else              v = goal[gr * 2 + (k - 384)];
        xbuf[k * 32 + r] = v;
    }
    __syncthreads();

    // ---- P2: context fp32 (256 units x 32 rows; thread = (u, 8-row chunk)) ----
    {
        const int u = t & 255, rh = t >> 8;       // rh 0..3
        float acc[8];
        float bp = b_proj[u];
#pragma unroll
        for (int rr = 0; rr < 8; ++rr) acc[rr] = bp;
        for (int k = 0; k < 386; ++k) {
            float wv = Wproj[u * 386 + k];
            const float* xr = &xbuf[k * 32 + rh * 8];
#pragma unroll
            for (int rr = 0; rr < 8; ++rr) acc[rr] = fmaf(xr[rr], wv, acc[rr]);
        }
#pragma unroll
        for (int rr = 0; rr < 8; ++rr) ctxL[u * 32 + rh * 8 + rr] = acc[rr];
    }
    __syncthreads();

    // ---- P3: write own uc-slice of h1(-1), h2(-1) slabs (parity 1) ----
    for (int idx = t; idx < 8192; idx += 1024) {
        int layer = idx >> 12;
        int j2 = idx & 4095;
        int f = j2 & 511, nt = (j2 >> 9) & 1, sb = (j2 >> 10) & 1, kl = j2 >> 11;
        int lane = f >> 3, j = f & 7;
        int k_in = ((lane >> 4) << 3) + j;
        int Ug = uc * 64 + kl * 32 + k_in;
        float v = ctxL[Ug * 32 + nt * 16 + (lane & 15)];
        _Float16 hi = (_Float16)v;
        u16 val = sb ? hbits((_Float16)(v - (float)hi)) : hbits(hi);
        int kt = uc * 2 + kl;
        st16_sc(Hb + hidx(bc, 1, layer) + ((kt * 2 + sb) * 2 + nt) * 512 + f, val);
    }
    waitcnt0();
    __syncthreads();
    if (t == 0) {
        __hip_atomic_store(fptr(flags, bc, 1, uc), 0, __ATOMIC_RELAXED, __HIP_MEMORY_SCOPE_AGENT);
        __hip_atomic_store(fptr(flags, bc, 0, uc), 0, __ATOMIC_RELAXED, __HIP_MEMORY_SCOPE_AGENT);
    }
    __syncthreads();

    // ---- P4: posF + onesF ----
    for (int idx = t; idx < 2048; idx += 1024) {
        int f = idx & 511, nt = (idx >> 9) & 1, sb = idx >> 10;
        int lane = f >> 3, j = f & 7;
        int k_in = ((lane >> 4) << 3) + j;
        u16 val = 0;
        if (k_in < 2) {
            float pv = cpos[(row0 + nt * 16 + (lane & 15)) * 2 + k_in];
            _Float16 hi = (_Float16)pv;
            val = sb ? hbits((_Float16)(pv - (float)hi)) : hbits(hi);
        }
        posF[(sb * 2 + nt) * 512 + f] = val;
    }
    if (t < 1024) {
        int f = t & 511, sb = t >> 9;
        int lane = f >> 3, j = f & 7;
        int k_in = ((lane >> 4) << 3) + j;
        onesF[sb * 512 + f] = (sb == 0 && k_in == 0) ? hbits((_Float16)1.0f) : (u16)0;
    }
    __syncthreads();

    // ---- P5a: stage X = h1(-1); G0c via MFMA ----
    if (t < 4) spin_ge(fptr(flags, bc, 0, t), 0);
    __syncthreads();
    stage32k(Hb + hidx(bc, 1, 0), X, t);
    __syncthreads();

    f32x4 G00 = {0,0,0,0}, G01 = {0,0,0,0};
#pragma unroll
    for (int kt = 0; kt < 8; ++kt) {
        f16x8 bh0 = *(const f16x8*)&X[((kt*2+0)*2+0)*512 + l*8];
        f16x8 bh1 = *(const f16x8*)&X[((kt*2+0)*2+1)*512 + l*8];
        f16x8 bl0 = *(const f16x8*)&X[((kt*2+1)*2+0)*512 + l*8];
        f16x8 bl1 = *(const f16x8*)&X[((kt*2+1)*2+1)*512 + l*8];
        const u16* p = AG0w + kt * 1024;
        f16x8 ah = *(const f16x8*)p, al = *(const f16x8*)(p + 512);
        G00 = MF(ah,bh0,G00); G00 = MF(ah,bl0,G00); G00 = MF(al,bh0,G00);
        G01 = MF(ah,bh1,G01); G01 = MF(ah,bl1,G01); G01 = MF(al,bh1,G01);
    }
    {
        f16x8 bh = *(const f16x8*)&onesF[l*8];
        f16x8 bl = *(const f16x8*)&onesF[512 + l*8];
        const u16* p = AG0w + 8 * 1024;
        f16x8 ah = *(const f16x8*)p, al = *(const f16x8*)(p + 512);
        G00 = MF(ah,bh,G00); G00 = MF(ah,bl,G00); G00 = MF(al,bh,G00);
        G01 = MF(ah,bh,G01); G01 = MF(ah,bl,G01); G01 = MF(al,bh,G01);
    }

    // ---- P5b: stage Y = h2(-1) ----
    if (t < 4) spin_ge(fptr(flags, bc, 1, t), 0);
    __syncthreads();
    stage32k(Hb + hidx(bc, 1, 1), Y, t);
    __syncthreads();

    float c1[2] = {0,0}, c2[2] = {0,0};

    // ================= time loop =================
    for (int s = 0; s < Tst; ++s) {
        const int par = s & 1;

        // ===== Phase A (pure local): L0 from retained X + posF -> h1(s) =====
        f32x4 a0 = G00, a1 = G01;
#pragma unroll
        for (int kt = 0; kt < 8; ++kt) {
            f16x8 bh0 = *(const f16x8*)&X[((kt*2+0)*2+0)*512 + l*8];
            f16x8 bh1 = *(const f16x8*)&X[((kt*2+0)*2+1)*512 + l*8];
            f16x8 bl0 = *(const f16x8*)&X[((kt*2+1)*2+0)*512 + l*8];
            f16x8 bl1 = *(const f16x8*)&X[((kt*2+1)*2+1)*512 + l*8];
            const u16* p = A0w + kt * 1024;
            f16x8 ah = *(const f16x8*)p, al = *(const f16x8*)(p + 512);
            a0 = MF(ah,bh0,a0); a0 = MF(ah,bl0,a0); a0 = MF(al,bh0,a0);
            a1 = MF(ah,bh1,a1); a1 = MF(ah,bl1,a1); a1 = MF(al,bh1,a1);
        }
        {   // pos column (kt 8)
            f16x8 bh0 = *(const f16x8*)&posF[(0*2+0)*512 + l*8];
            f16x8 bh1 = *(const f16x8*)&posF[(0*2+1)*512 + l*8];
            f16x8 bl0 = *(const f16x8*)&posF[(1*2+0)*512 + l*8];
            f16x8 bl1 = *(const f16x8*)&posF[(1*2+1)*512 + l*8];
            const u16* p = A0w + 8 * 1024;
            f16x8 ah = *(const f16x8*)p, al = *(const f16x8*)(p + 512);
            a0 = MF(ah,bh0,a0); a0 = MF(ah,bl0,a0); a0 = MF(al,bh0,a0);
            a1 = MF(ah,bh1,a1); a1 = MF(ah,bl1,a1); a1 = MF(al,bh1,a1);
        }
        {
            float h1n[2];
            h1n[0] = lstm_out(a0, c1[0]);
            h1n[1] = lstm_out(a1, c1[1]);
            const int U   = w * 4 + (l >> 4);
            const int ktl = U >> 5, ki = U & 31;
            const int f   = ((l & 15) + 16 * (ki >> 3)) * 8 + (ki & 7);
#pragma unroll
            for (int nt = 0; nt < 2; ++nt) {
                float v = h1n[nt];
                _Float16 hi = (_Float16)v;
                hSt[((ktl*2+0)*2+nt)*512 + f] = hbits(hi);
                hSt[((ktl*2+1)*2+nt)*512 + f] = hbits((_Float16)(v - (float)hi));
            }
        }
        __syncthreads();                                  // hSt ready; X reads done
        if (t < 512) st4_sc((u32x4*)(Hb + hidx(bc, par, 0) + uc * 4096) + t, ((const u32x4*)hSt)[t]);
        waitcnt0();
        __syncthreads();                                  // slice stored
        if (t == 0) __hip_atomic_store(fptr(flags, bc, 0, uc), s + 1,
                                       __ATOMIC_RELAXED, __HIP_MEMORY_SCOPE_AGENT);

        // ===== Phase B: stage X = h1(s); L1 -> h2(s) =====
        if (t < 4) spin_ge(fptr(flags, bc, 0, t), s + 1);
        __syncthreads();
        stage32k(Hb + hidx(bc, par, 0), X, t);            // X <- h1(s)
        __syncthreads();
        a0 = f32x4{0,0,0,0}; a1 = f32x4{0,0,0,0};
#pragma unroll
        for (int kt = 0; kt < 8; ++kt) {
            f16x8 bh0 = *(const f16x8*)&X[((kt*2+0)*2+0)*512 + l*8];
            f16x8 bh1 = *(const f16x8*)&X[((kt*2+0)*2+1)*512 + l*8];
            f16x8 bl0 = *(const f16x8*)&X[((kt*2+1)*2+0)*512 + l*8];
            f16x8 bl1 = *(const f16x8*)&X[((kt*2+1)*2+1)*512 + l*8];
            const u16* p = A1w + kt * 1024;
            f16x8 ah = *(const f16x8*)p, al = *(const f16x8*)(p + 512);
            a0 = MF(ah,bh0,a0); a0 = MF(ah,bl0,a0); a0 = MF(al,bh0,a0);
            a1 = MF(ah,bh1,a1); a1 = MF(ah,bl1,a1); a1 = MF(al,bh1,a1);
        }
#pragma unroll
        for (int kt = 8; kt < 16; ++kt) {                 // Y = h2(s-1), retained from C(s-1)
            const int ks = kt - 8;
            f16x8 bh0 = *(const f16x8*)&Y[((ks*2+0)*2+0)*512 + l*8];
            f16x8 bh1 = *(const f16x8*)&Y[((ks*2+0)*2+1)*512 + l*8];
            f16x8 bl0 = *(const f16x8*)&Y[((ks*2+1)*2+0)*512 + l*8];
            f16x8 bl1 = *(const f16x8*)&Y[((ks*2+1)*2+1)*512 + l*8];
            const u16* p = A1w + kt * 1024;
            f16x8 ah = *(const f16x8*)p, al = *(const f16x8*)(p + 512);
            a0 = MF(ah,bh0,a0); a0 = MF(ah,bl0,a0); a0 = MF(al,bh0,a0);
            a1 = MF(ah,bh1,a1); a1 = MF(ah,bl1,a1); a1 = MF(al,bh1,a1);
        }
        {   // bias column (kt 16)
            f16x8 bh = *(const f16x8*)&onesF[l*8];
            f16x8 bl = *(const f16x8*)&onesF[512 + l*8];
            const u16* p = A1w + 16 * 1024;
            f16x8 ah = *(const f16x8*)p, al = *(const f16x8*)(p + 512);
            a0 = MF(ah,bh,a0); a0 = MF(ah,bl,a0); a0 = MF(al,bh,a0);
            a1 = MF(ah,bh,a1); a1 = MF(ah,bl,a1); a1 = MF(al,bh,a1);
        }
        {
            float h2n[2];
            h2n[0] = lstm_out(a0, c2[0]);
            h2n[1] = lstm_out(a1, c2[1]);
            const int U   = w * 4 + (l >> 4);
            const int ktl = U >> 5, ki = U & 31;
            const int f   = ((l & 15) + 16 * (ki >> 3)) * 8 + (ki & 7);
#pragma unroll
            for (int nt = 0; nt < 2; ++nt) {
                float v = h2n[nt];
                _Float16 hi = (_Float16)v;
                hSt[((ktl*2+0)*2+nt)*512 + f] = hbits(hi);
                hSt[((ktl*2+1)*2+nt)*512 + f] = hbits((_Float16)(v - (float)hi));
            }
        }
        __syncthreads();                                  // hSt ready
        if (t < 512) st4_sc((u32x4*)(Hb + hidx(bc, par, 1) + uc * 4096) + t, ((const u32x4*)hSt)[t]);
        waitcnt0();
        __syncthreads();                                  // slice stored
        if (t == 0) __hip_atomic_store(fptr(flags, bc, 1, uc), s + 1,
                                       __ATOMIC_RELAXED, __HIP_MEMORY_SCOPE_AGENT);

        // ===== Phase C: stage Y = h2(s); head -> out[s], posF(s+1) =====
        if (t < 4) spin_ge(fptr(flags, bc, 1, t), s + 1);
        __syncthreads();
        stage32k(Hb + hidx(bc, par, 1), Y, t);            // Y <- h2(s), retained for B(s+1)
        __syncthreads();
        if (w < 8) {
            f32x4 pv = {0,0,0,0};
#pragma unroll
            for (int kt = 0; kt < 8; ++kt) {
                f16x8 bh = *(const f16x8*)&Y[((kt*2+0)*2+nth)*512 + l*8];
                f16x8 bl = *(const f16x8*)&Y[((kt*2+1)*2+nth)*512 + l*8];
                const u16* p = AHw + kt * 1024;
                f16x8 ah = *(const f16x8*)p, al = *(const f16x8*)(p + 512);
                pv = MF(ah, bh, pv); pv = MF(ah, bl, pv); pv = MF(al, bh, pv);
            }
            {
                f16x8 bh = *(const f16x8*)&onesF[l*8];
                f16x8 bl = *(const f16x8*)&onesF[512 + l*8];
                const u16* p = AHw + 8 * 1024;
                f16x8 ah = *(const f16x8*)p, al = *(const f16x8*)(p + 512);
                pv = MF(ah, bh, pv); pv = MF(ah, bl, pv); pv = MF(al, bh, pv);
            }
#pragma unroll
            for (int r = 0; r < 4; ++r) pv[r] = fmaxf(pv[r], 0.f);
            const int mrow = nth * 16 + (l & 15);
            *(f32x4*)&mlpL[mrow * 68 + (w & 3) * 16 + (l >> 4) * 4] = pv;
        }
        __syncthreads();                                  // mlpL ready
        if (t < 64) {
            const int r = t >> 1, o = t & 1;
            float a = b_out2[o];
#pragma unroll 8
            for (int k = 0; k < 64; ++k) a = fmaf(mlpL[r * 68 + k], Wout2[o * 64 + k], a);
            if (uc == 0) out[((size_t)(row0 + r) * Tst + s) * 2 + o] = a;
            _Float16 hi = (_Float16)a;
            posF[(0 * 2 + (r >> 4)) * 512 + (r & 15) * 8 + o] = hbits(hi);
            posF[(2 + (r >> 4)) * 512 + (r & 15) * 8 + o] = hbits((_Float16)(a - (float)hi));
        }
        __syncthreads();                                  // posF(s+1) ready
    }
}

// ---------------- launch ----------------
extern "C" void kernel_launch(void* const* d_in, const int* in_sizes, int n_in,
                              void* d_out, int out_size, void* d_ws, size_t ws_size,
                              hipStream_t stream) {
    const float* env   = (const float*)d_in[0];
    const float* hist  = (const float*)d_in[1];
    const float* goal  = (const float*)d_in[2];
    const float* cpos  = (const float*)d_in[3];
    const float* Wproj = (const float*)d_in[4];
    const float* bproj = (const float*)d_in[5];
    const float* Wih0  = (const float*)d_in[6];
    const float* Whh0  = (const float*)d_in[7];
    const float* bih0  = (const float*)d_in[8];
    const float* bhh0  = (const float*)d_in[9];
    const float* Wih1  = (const float*)d_in[10];
    const float* Whh1  = (const float*)d_in[11];
    const float* bih1  = (const float*)d_in[12];
    const float* bhh1  = (const float*)d_in[13];
    const float* Wout1 = (const float*)d_in[14];
    const float* bout1 = (const float*)d_in[15];
    const float* Wout2 = (const float*)d_in[16];
    const float* bout2 = (const float*)d_in[17];

    if (ws_size < WS_BYTES) return;
    u16* wsu = (u16*)d_ws;

    (void)hipMemsetAsync((char*)d_ws + (size_t)OFF_FLG * 2, 0xFF,
                         (size_t)N_FLAGS_I * sizeof(int), stream);

    prep_kernel<<<(WS_U16 + 255) / 256, 256, 0, stream>>>(
        Wih0, Whh0, bih0, bhh0, Wih1, Whh1, bih1, bhh1, Wout1, bout1, wsu);

    lstm_main<<<256, 1024, 0, stream>>>(
        env, hist, goal, cpos, Wproj, bproj, Wout2, bout2, wsu, (float*)d_out);
}